// Round 3
// baseline (166.164 us; speedup 1.0000x reference)
//
#include <hip/hip_runtime.h>

typedef _Float16 half8_t __attribute__((ext_vector_type(8)));
typedef _Float16 half4_t __attribute__((ext_vector_type(4)));
typedef float    float4_t __attribute__((ext_vector_type(4)));

#define N_TILES 1024
#define PTS     256
#define IN_F    256
#define OUT_F   256
#define BM      64          // rows per block (quarter tile)
#define BK      32
#define LDK     40          // BK + 8 fp16 pad -> 80 B rows (20-dword stride spreads banks)
#define NSTEP   (IN_F / BK) // 8
#define OMEGA_C 30.0f

// Barrier WITHOUT vmcnt(0) drain: LDS ops must complete (lgkmcnt), global loads
// stay in flight across it (T4 counted-vmcnt essence). __syncthreads would
// drain vmcnt(0) and kill the depth-2 pipeline.
#define BARRIER() do {                                        \
    asm volatile("s_waitcnt lgkmcnt(0)" ::: "memory");        \
    __builtin_amdgcn_s_barrier();                             \
    asm volatile("" ::: "memory");                            \
  } while (0)

// B-write swizzle: 16B k-group g at row n lives at physical group g^((n>>3)&3).
#define BSWZ(g, n) (((g) ^ (((n) >> 3) & 3)))

__global__ __launch_bounds__(512, 4)
void siren_tile_gemm(const float* __restrict__ x,
                     const float* __restrict__ w,
                     const float* __restrict__ bias,
                     const void* __restrict__ idx_raw,
                     float* __restrict__ out) {
  __shared__ __align__(16) _Float16 Al[2][BM][LDK];     // 10,240 B
  __shared__ __align__(16) _Float16 Bl[2][OUT_F][LDK];  // 40,960 B (total 51,200 -> 2 blocks/CU)

  const int tid = threadIdx.x;

  // XCD swizzle: the 4 row-quarters of a tile all map to the same XCD (b mod 8
  // fixed) and dispatch near-simultaneously -> W shared through that XCD's L2.
  const int b    = blockIdx.x;          // 0..4095
  const int xcd  = b & 7;
  const int rest = b >> 3;              // 0..511
  const int tile = xcd + 8 * (rest >> 2);
  const int mq   = rest & 3;            // row-quarter

  // indices dtype self-detect (int64 per reference; int32 if demoted).
  const int hiw  = ((const int*)idx_raw)[2 * (tid & 63) + 1];
  const bool is32 = __any(hiw != 0);
  const int ch = is32 ? ((const int*)idx_raw)[tile]
                      : (int)(((const long long*)idx_raw)[tile]);

  const float* __restrict__ Xg = x + (size_t)tile * (PTS * IN_F) + (size_t)mq * BM * IN_F;
  const float* __restrict__ Wg = w + (size_t)ch * (IN_F * OUT_F);
  float*       __restrict__ Og = out + (size_t)tile * (PTS * OUT_F) + (size_t)mq * BM * OUT_F;

  // A staging: 512 thr cover 64 rows x 32 k : 1 float4 each
  const int a_row = tid >> 3;          // 0..63
  const int a_col = (tid & 7) * 4;     // f32 col in step
  // B staging: wave kb=tid>>6 loads rows {4kb+j}, cols 4*(tid&63); 4x4 reg transpose
  const int b_kb  = tid >> 6;
  const int b_nb  = tid & 63;

  float4_t acc[2][4];
#pragma unroll
  for (int m = 0; m < 2; ++m)
#pragma unroll
    for (int n = 0; n < 4; ++n)
      acc[m][n] = (float4_t){0.f, 0.f, 0.f, 0.f};

  // depth-2 register pipeline: slot t&1 holds loads of k-step t
  float4_t aS[2];
  float4_t bS[2][4];

#define ISSUE(slot, s)                                                          \
  do {                                                                          \
    const int k0_ = (s) * BK;                                                   \
    aS[slot] = *(const float4_t*)(Xg + (size_t)a_row * IN_F + k0_ + a_col);     \
    _Pragma("unroll")                                                           \
    for (int j = 0; j < 4; ++j)                                                 \
      bS[slot][j] = *(const float4_t*)(Wg + (size_t)(k0_ + b_kb * 4 + j) * OUT_F + b_nb * 4); \
  } while (0)

#define STORE_LDS(slot, buf)                                                    \
  do {                                                                          \
    half4_t ha_ = {(_Float16)aS[slot].x, (_Float16)aS[slot].y,                  \
                   (_Float16)aS[slot].z, (_Float16)aS[slot].w};                 \
    *(half4_t*)&Al[buf][a_row][a_col] = ha_;                                    \
    _Pragma("unroll")                                                           \
    for (int i = 0; i < 4; ++i) {                                               \
      const int n_ = b_nb * 4 + i;                                              \
      half4_t hb_ = {(_Float16)bS[slot][0][i], (_Float16)bS[slot][1][i],        \
                     (_Float16)bS[slot][2][i], (_Float16)bS[slot][3][i]};       \
      *(half4_t*)&Bl[buf][n_][BSWZ(b_kb >> 1, n_) * 8 + (b_kb & 1) * 4] = hb_;  \
    }                                                                           \
  } while (0)

  // ---- prologue: issue steps 0 and 1, commit step 0 to LDS ----
  ISSUE(0, 0);
  ISSUE(1, 1);
  STORE_LDS(0, 0);   // compiler emits counted vmcnt (step-1 loads stay in flight)
  BARRIER();

  const int lane = tid & 63;
  const int wid  = tid >> 6;
  const int wm   = (wid >> 2) * 32;  // wave M origin (0/32)
  const int wn   = (wid & 3) * 64;   // wave N origin
  const int fr   = lane & 15;
  const int kg   = lane >> 4;

#pragma unroll
  for (int s = 0; s < NSTEP; ++s) {
    const int cur = s & 1;

    half8_t af[2], bf[4];
#pragma unroll
    for (int m = 0; m < 2; ++m)
      af[m] = *(const half8_t*)&Al[cur][wm + m * 16 + fr][kg * 8];
#pragma unroll
    for (int n = 0; n < 4; ++n) {
      const int r = wn + n * 16 + fr;
      bf[n] = *(const half8_t*)&Bl[cur][r][BSWZ(kg, r) * 8];
    }

#pragma unroll
    for (int m = 0; m < 2; ++m)
#pragma unroll
      for (int n = 0; n < 4; ++n)
        acc[m][n] = __builtin_amdgcn_mfma_f32_16x16x32_f16(af[m], bf[n], acc[m][n], 0, 0, 0);

    if (s + 2 < NSTEP) ISSUE(cur, s + 2);      // slot cur is free (its data is in LDS)
    if (s + 1 < NSTEP) {
      STORE_LDS(cur ^ 1, cur ^ 1);             // waits for s+1 arrivals only (counted vmcnt)
      BARRIER();
    }
  }

  // ---- epilogue: bias + sin (C/D: col=lane&15, row=(lane>>4)*4+j) ----
  float bv[4];
#pragma unroll
  for (int n = 0; n < 4; ++n) bv[n] = OMEGA_C * bias[wn + n * 16 + fr];

#pragma unroll
  for (int m = 0; m < 2; ++m) {
#pragma unroll
    for (int n = 0; n < 4; ++n) {
#pragma unroll
      for (int j = 0; j < 4; ++j) {
        const int row = wm + m * 16 + kg * 4 + j;
        const int col = wn + n * 16 + fr;
        Og[(size_t)row * OUT_F + col] = __sinf(fmaf(OMEGA_C, acc[m][n][j], bv[n]));
      }
    }
  }
}

extern "C" void kernel_launch(void* const* d_in, const int* in_sizes, int n_in,
                              void* d_out, int out_size, void* d_ws, size_t ws_size,
                              hipStream_t stream) {
  const float* x    = (const float*)d_in[0];
  const float* w    = (const float*)d_in[1];
  const float* bias = (const float*)d_in[2];
  const void*  idx  = d_in[3];
  float*       out  = (float*)d_out;

  siren_tile_gemm<<<N_TILES * 4, 512, 0, stream>>>(x, w, bias, idx, out);
}